// Round 6
// baseline (118.179 us; speedup 1.0000x reference)
//
#include <hip/hip_runtime.h>

#define C_IN   64
#define HW_DIM 64
#define C_OUT  128
#define NG     8
#define KSPL   4608     // 576 * 8
#define BM     64       // pixels per block = one image row
#define NSPL_STEPS 72   // KSPL / 64
#define NSTEPS 81
#define NPAD   66
#define NEXP   (8 * C_IN * NPAD * NPAD)   // 2,230,272 padded elements

// d_ws layout (bytes)
#define WT_BYTES 1327104                  // 81*128*64*2
#define XE_OFF   WT_BYTES
#define XE_BYTES (NEXP * NG * 2)          // 35,684,352
#define SE_OFF   (XE_OFF + XE_BYTES)

typedef __attribute__((ext_vector_type(8))) __bf16 bf16x8;
typedef __attribute__((ext_vector_type(4))) float  f32x4;

// --------------------------------------------------------------------------
// Weight prep: pack spline_w ++ base_w into per-wave MFMA-fragment order for
// the 8-wave gemm: wt4[step][wid(8)][ks(2)][lane(64)][8], value = W[co][k],
// co = wid*16 + (lane&15), k = step*64 + ks*32 + (lane>>4)*8 + e.
// A wave's 2 frag loads per step are 2 consecutive 1KB segments.
// --------------------------------------------------------------------------
__global__ __launch_bounds__(256)
void prep_wt(const float* __restrict__ sw, const float* __restrict__ bw,
             __bf16* __restrict__ wt4)
{
  const int step = blockIdx.x;
  const int t    = threadIdx.x;
  const int lane = t & 63;
  const int l15  = lane & 15;
  const int g4   = lane >> 4;
#pragma unroll
  for (int i = 0; i < 2; ++i) {
    const int wid = (t >> 6) + i * 4;
    const int co  = wid * 16 + l15;
#pragma unroll
    for (int ks = 0; ks < 2; ++ks) {
      bf16x8 v;
#pragma unroll
      for (int e = 0; e < 8; ++e) {
        const int k = step * 64 + ks * 32 + g4 * 8 + e;
        float f;
        if (k < KSPL) f = sw[(size_t)k * C_OUT + co];
        else          f = bw[(size_t)(k - KSPL) * C_OUT + co];
        v[e] = (__bf16)f;
      }
      *(bf16x8*)(wt4 + (size_t)step * 8192 + wid * 1024 + ks * 512 + lane * 8) = v;
    }
  }
}

// --------------------------------------------------------------------------
// Basis/silu expansion: XE[bc][yp][xp][8], SE[bc][yp][xp]; halo = p=0 values.
// --------------------------------------------------------------------------
__global__ __launch_bounds__(256)
void expand(const float* __restrict__ x, const float* __restrict__ grid,
            __bf16* __restrict__ xe, __bf16* __restrict__ se)
{
  const int idx = blockIdx.x * 256 + threadIdx.x;
  if (idx >= NEXP) return;
  const int xp = idx % NPAD;
  const int r  = idx / NPAD;
  const int yp = r % NPAD;
  const int bc = r / NPAD;

  float p = 0.f;
  if (xp >= 1 && xp <= HW_DIM && yp >= 1 && yp <= HW_DIM)
    p = x[(size_t)bc * (HW_DIM * HW_DIM) + (yp - 1) * HW_DIM + (xp - 1)];

  bf16x8 v;
#pragma unroll
  for (int g = 0; g < NG; ++g) {
    const float z = 1.75f * (p - grid[g]);
    v[g] = (__bf16)__expf(-z * z);
  }
  *(bf16x8*)(xe + (size_t)idx * NG) = v;
  const float e = __expf(-p);
  se[idx] = (__bf16)(p * __builtin_amdgcn_rcpf(1.f + e));
}

// --------------------------------------------------------------------------
// GEMM: 512 blocks (1 image row) x 512 threads (8 waves, each 64px x 16co)
// -> 4 waves/SIMD. Spline phase (72 steps): barrier-free, all frags direct
// global->reg, unroll-by-2 software pipeline. Base phase (9 steps): LDS.
// --------------------------------------------------------------------------
__global__ __launch_bounds__(512, 4)
void kan_gemm(const __bf16* __restrict__ xe, const __bf16* __restrict__ se,
              const __bf16* __restrict__ wt4, const float* __restrict__ base_b,
              float* __restrict__ out)
{
  __shared__ __align__(16) __bf16 As[2][BM][64];   // base phase only, 16 KB
  __shared__ int tbl[576];                         // c*4356 + kh*66 + kw

  const int t    = threadIdx.x;
  const int lane = t & 63;
  const int wid  = t >> 6;              // 0..7
  const int l15  = lane & 15;
  const int g4   = lane >> 4;

  // bijective XCD swizzle: 512 blocks = 8 XCDs x 64 -> one image per XCD
  const int bid = blockIdx.x;
  const int swz = (bid & 7) * 64 + (bid >> 3);
  const int b   = swz >> 6;             // image
  const int y0  = swz & 63;             // image row

  for (int f = t; f < 576; f += 512) {
    const int c  = f / 9;
    const int j  = f - 9 * c;
    const int kh = j / 3;
    const int kw = j - 3 * kh;
    tbl[f] = c * 4356 + kh * 66 + kw;
  }

  const int F0  = b * 278784 + y0 * 66 + l15;       // A-frag pixel base
  const int F0s = b * 278784 + y0 * 66 + (t & 63);  // base-stage pixel base

  f32x4 acc[4];                         // 4 px-blocks x 16 co
#pragma unroll
  for (int m = 0; m < 4; ++m) acc[m] = f32x4{0.f, 0.f, 0.f, 0.f};

  auto loadB = [&](bf16x8 wf[2], int step) {
    const __bf16* wb = wt4 + (size_t)step * 8192 + wid * 1024 + lane * 8;
#pragma unroll
    for (int ks = 0; ks < 2; ++ks)
      wf[ks] = *(const bf16x8*)(wb + ks * 512);
  };

  auto loadA = [&](bf16x8 xf[4][2], int step) {
#pragma unroll
    for (int ks = 0; ks < 2; ++ks) {
      const int f = step * 8 + ks * 4 + g4;
      const __bf16* ab = xe + ((size_t)(F0 + tbl[f])) * 8;
#pragma unroll
      for (int m = 0; m < 4; ++m)                   // px = m*16+l15
        xf[m][ks] = *(const bf16x8*)(ab + m * 128);
    }
  };

  auto mfmaS = [&](bf16x8 xf[4][2], bf16x8 wf[2]) {
#pragma unroll
    for (int ks = 0; ks < 2; ++ks)
#pragma unroll
      for (int m = 0; m < 4; ++m)
        acc[m] = __builtin_amdgcn_mfma_f32_16x16x32_bf16(
            wf[ks], xf[m][ks], acc[m], 0, 0, 0);
  };

  __syncthreads();                      // tbl ready

  // ---- spline phase: barrier-free, 1-step-ahead pipeline ----
  bf16x8 xfA[4][2], xfB[4][2], wfA[2], wfB[2];
  loadA(xfA, 0); loadB(wfA, 0);
  for (int s = 0; s < NSPL_STEPS - 2; s += 2) {
    loadA(xfB, s + 1); loadB(wfB, s + 1);
    mfmaS(xfA, wfA);
    loadA(xfA, s + 2); loadB(wfA, s + 2);
    mfmaS(xfB, wfB);
  }
  loadA(xfB, NSPL_STEPS - 1); loadB(wfB, NSPL_STEPS - 1);
  mfmaS(xfA, wfA);
  mfmaS(xfB, wfB);

  // ---- base phase: silu(p) patches via LDS (9 steps) ----
  auto stageA = [&](int buf, int bs) {
    const int q  = t >> 6;              // granule 0..7
    const int px = t & 63;
    bf16x8 v;
#pragma unroll
    for (int jj = 0; jj < 8; ++jj) {
      const int f = (bs - NSPL_STEPS) * 64 + q * 8 + jj;
      v[jj] = se[(size_t)(F0s + tbl[f])];
    }
    *(bf16x8*)(&As[buf][px][(q ^ (px & 7)) * 8]) = v;
  };

  stageA(0, NSPL_STEPS);
  __syncthreads();
  for (int bs = NSPL_STEPS; bs < NSTEPS; ++bs) {
    const int cb = (bs - NSPL_STEPS) & 1;
    if (bs + 1 < NSTEPS) stageA(cb ^ 1, bs + 1);
    loadB(wfA, bs);
    bf16x8 xf[4][2];
#pragma unroll
    for (int ks = 0; ks < 2; ++ks)
#pragma unroll
      for (int m = 0; m < 4; ++m) {
        const int pr = m * 16 + l15;
        xf[m][ks] = *(const bf16x8*)(&As[cb][pr][(((ks * 4 + g4) ^ (pr & 7)) * 8)]);
      }
    mfmaS(xf, wfA);
    __syncthreads();
  }

  // ---- epilogue: D[co][pix]; l15 -> consecutive x: coalesced ----
  const int co = wid * 16 + g4 * 4;
#pragma unroll
  for (int m = 0; m < 4; ++m) {
    const int pl = m * 16 + l15;
    float* o = out + (size_t)(b * C_OUT + co) * 4096 + y0 * 64 + pl;
#pragma unroll
    for (int i = 0; i < 4; ++i)
      o[(size_t)i * 4096] = acc[m][i] + base_b[co + i];
  }
}

extern "C" void kernel_launch(void* const* d_in, const int* in_sizes, int n_in,
                              void* d_out, int out_size, void* d_ws, size_t ws_size,
                              hipStream_t stream) {
  const float* x    = (const float*)d_in[0];
  const float* grid = (const float*)d_in[1];
  const float* sw   = (const float*)d_in[2];
  const float* bw   = (const float*)d_in[3];
  const float* bb   = (const float*)d_in[4];
  float* out = (float*)d_out;

  __bf16* wt4 = (__bf16*)d_ws;
  __bf16* xe  = (__bf16*)((char*)d_ws + XE_OFF);
  __bf16* se  = (__bf16*)((char*)d_ws + SE_OFF);

  prep_wt<<<NSTEPS, 256, 0, stream>>>(sw, bw, wt4);
  expand<<<(NEXP + 255) / 256, 256, 0, stream>>>(x, grid, xe, se);
  kan_gemm<<<512, 512, 0, stream>>>(xe, se, wt4, bb, out);
}

// Round 7
// 87.362 us; speedup vs baseline: 1.3527x; 1.3527x over previous
//
#include <hip/hip_runtime.h>

#define C_IN   64
#define HW_DIM 64
#define C_OUT  128
#define NG     8
#define KSPL   4608     // 576 * 8
#define BM     64       // pixels per block = one image row
#define NSPL_STEPS 72   // KSPL / 64
#define NSTEPS 81
#define NPAD   66
#define NEXP   (8 * C_IN * NPAD * NPAD)   // 2,230,272 padded elements

// d_ws layout (bytes)
#define WT_BYTES 1327104                  // 81*128*64*2
#define XE_OFF   WT_BYTES
#define XE_BYTES (NEXP * NG * 2)          // 35,684,352
#define SE_OFF   (XE_OFF + XE_BYTES)

typedef __attribute__((ext_vector_type(8))) __bf16 bf16x8;
typedef __attribute__((ext_vector_type(4))) float  f32x4;

// --------------------------------------------------------------------------
// Weight prep: pack spline_w ++ base_w into per-wave MFMA-fragment order for
// the 4-wave gemm: wt3[step][wc(4)][n(2)][ks(2)][lane(64)][8], value=W[co][k],
// co = wc*32 + n*16 + (lane&15), k = step*64 + ks*32 + (lane>>4)*8 + e.
// --------------------------------------------------------------------------
__global__ __launch_bounds__(256)
void prep_wt(const float* __restrict__ sw, const float* __restrict__ bw,
             __bf16* __restrict__ wt3)
{
  const int step = blockIdx.x;
  const int t    = threadIdx.x;
  const int wc   = t >> 6;
  const int lane = t & 63;
  const int l15  = lane & 15;
  const int g4   = lane >> 4;
#pragma unroll
  for (int n = 0; n < 2; ++n)
#pragma unroll
    for (int ks = 0; ks < 2; ++ks) {
      const int co = wc * 32 + n * 16 + l15;
      bf16x8 v;
#pragma unroll
      for (int e = 0; e < 8; ++e) {
        const int k = step * 64 + ks * 32 + g4 * 8 + e;
        float f;
        if (k < KSPL) f = sw[(size_t)k * C_OUT + co];
        else          f = bw[(size_t)(k - KSPL) * C_OUT + co];
        v[e] = (__bf16)f;
      }
      *(bf16x8*)(wt3 + (size_t)step * 8192 + wc * 2048 + (n * 2 + ks) * 512
                 + lane * 8) = v;
    }
}

// --------------------------------------------------------------------------
// Basis/silu expansion: XE[bc][yp][xp][8], SE[bc][yp][xp]; halo = p=0 values.
// --------------------------------------------------------------------------
__global__ __launch_bounds__(256)
void expand(const float* __restrict__ x, const float* __restrict__ grid,
            __bf16* __restrict__ xe, __bf16* __restrict__ se)
{
  const int idx = blockIdx.x * 256 + threadIdx.x;
  if (idx >= NEXP) return;
  const int xp = idx % NPAD;
  const int r  = idx / NPAD;
  const int yp = r % NPAD;
  const int bc = r / NPAD;

  float p = 0.f;
  if (xp >= 1 && xp <= HW_DIM && yp >= 1 && yp <= HW_DIM)
    p = x[(size_t)bc * (HW_DIM * HW_DIM) + (yp - 1) * HW_DIM + (xp - 1)];

  bf16x8 v;
#pragma unroll
  for (int g = 0; g < NG; ++g) {
    const float z = 1.75f * (p - grid[g]);
    v[g] = (__bf16)__expf(-z * z);
  }
  *(bf16x8*)(xe + (size_t)idx * NG) = v;
  const float e = __expf(-p);
  se[idx] = (__bf16)(p * __builtin_amdgcn_rcpf(1.f + e));
}

static __device__ __forceinline__ void gload16(const __bf16* g, __bf16* l) {
  __builtin_amdgcn_global_load_lds(
      (const __attribute__((address_space(1))) void*)g,
      (__attribute__((address_space(3))) void*)l, 16, 0, 0);
}

// --------------------------------------------------------------------------
// GEMM: 512 blocks (1 image row) x 4 waves (64px x 32co each).
// Spline (72 steps): A staged ONCE per block via global_load_lds into a
// double-buffered swizzled LDS tile (8KB/step); B direct global->reg with
// unroll-by-2 prefetch; one barrier per step. Base (9 steps): LDS gathers.
// --------------------------------------------------------------------------
__global__ __launch_bounds__(256, 2)
void kan_gemm(const __bf16* __restrict__ xe, const __bf16* __restrict__ se,
              const __bf16* __restrict__ wt3, const float* __restrict__ base_b,
              float* __restrict__ out)
{
  __shared__ __align__(16) __bf16 As[2][BM][64];   // 16 KB, both phases
  __shared__ int tbl[576];                         // c*4356 + kh*66 + kw

  const int t    = threadIdx.x;
  const int lane = t & 63;
  const int wid  = t >> 6;              // 0..3
  const int l15  = lane & 15;
  const int g4   = lane >> 4;

  // bijective XCD swizzle: 512 blocks = 8 XCDs x 64 -> one image per XCD
  const int bid = blockIdx.x;
  const int swz = (bid & 7) * 64 + (bid >> 3);
  const int b   = swz >> 6;             // image
  const int y0  = swz & 63;             // image row

  for (int f = t; f < 576; f += 256) {
    const int c  = f / 9;
    const int j  = f - 9 * c;
    const int kh = j / 3;
    const int kw = j - 3 * kh;
    tbl[f] = c * 4356 + kh * 66 + kw;
  }

  const int ROW = b * 278784 + y0 * 66;

  // A-staging: granule s = pass*256 + t holds (px = s>>3, gslot = s&7);
  // slot (px,gslot) must contain feature q = gslot ^ (px&7)  (G21 pre-swizzle)
  const int qsrc = (lane & 7) ^ ((lane >> 3) & 7);   // = gslot ^ (px&7)
  const int pbase = (wid << 3) + (lane >> 3);        // px for pass 0

  f32x4 acc[2][4];
#pragma unroll
  for (int n = 0; n < 2; ++n)
#pragma unroll
    for (int m = 0; m < 4; ++m)
      acc[n][m] = f32x4{0.f, 0.f, 0.f, 0.f};

  auto stageA = [&](int buf, int step) {
    const int off = ROW + tbl[step * 8 + qsrc] + pbase;
    __bf16* dst = &As[buf][0][0] + t * 8;
    gload16(xe + (size_t)off * 8,        dst);
    gload16(xe + (size_t)(off + 32) * 8, dst + 2048);   // pass 1: px += 32
  };

  auto loadB = [&](bf16x8 wf[2][2], int step) {
    const __bf16* wb = wt3 + (size_t)step * 8192 + wid * 2048 + lane * 8;
#pragma unroll
    for (int n = 0; n < 2; ++n)
#pragma unroll
      for (int ks = 0; ks < 2; ++ks)
        wf[n][ks] = *(const bf16x8*)(wb + (n * 2 + ks) * 512);
  };

  auto compute = [&](int buf, bf16x8 wf[2][2]) {
    bf16x8 xf[4][2];
#pragma unroll
    for (int ks = 0; ks < 2; ++ks)
#pragma unroll
      for (int m = 0; m < 4; ++m) {
        const int pr = m * 16 + l15;
        xf[m][ks] = *(const bf16x8*)(&As[buf][pr][(((ks * 4 + g4) ^ (pr & 7)) * 8)]);
      }
#pragma unroll
    for (int ks = 0; ks < 2; ++ks)
#pragma unroll
      for (int n = 0; n < 2; ++n)
#pragma unroll
        for (int m = 0; m < 4; ++m)
          acc[n][m] = __builtin_amdgcn_mfma_f32_16x16x32_bf16(
              wf[n][ks], xf[m][ks], acc[n][m], 0, 0, 0);
  };

  __syncthreads();                      // tbl ready

  // ---- spline phase: double-buffered, 1 barrier/step ----
  bf16x8 wfA[2][2], wfB[2][2];
  stageA(0, 0); loadB(wfA, 0);
  __syncthreads();                      // A(0) in LDS
  for (int s = 0; s < NSPL_STEPS; s += 2) {
    if (s + 1 < NSPL_STEPS) { stageA(1, s + 1); loadB(wfB, s + 1); }
    compute(0, wfA);
    __syncthreads();
    if (s + 2 < NSPL_STEPS) { stageA(0, s + 2); loadB(wfA, s + 2); }
    compute(1, wfB);
    __syncthreads();
  }

  // ---- base phase: silu(p) patches via LDS (9 steps) ----
  const int ROWs = ROW + (t & 63);
  auto stageBase = [&](int buf, int bs) {
    const int px = t & 63;
#pragma unroll
    for (int h = 0; h < 2; ++h) {
      const int q = (t >> 6) + h * 4;   // granule 0..7 over 2 passes
      bf16x8 v;
#pragma unroll
      for (int jj = 0; jj < 8; ++jj) {
        const int f = (bs - NSPL_STEPS) * 64 + q * 8 + jj;
        v[jj] = se[(size_t)(ROWs + tbl[f])];
      }
      *(bf16x8*)(&As[buf][px][(q ^ (px & 7)) * 8]) = v;
    }
  };

  stageBase(0, NSPL_STEPS);
  __syncthreads();
  for (int bs = NSPL_STEPS; bs < NSTEPS; ++bs) {
    const int cb = (bs - NSPL_STEPS) & 1;
    if (bs + 1 < NSTEPS) stageBase(cb ^ 1, bs + 1);
    loadB(wfA, bs);
    compute(cb, wfA);
    __syncthreads();
  }

  // ---- epilogue: D[co][pix]; l15 -> consecutive x: coalesced ----
#pragma unroll
  for (int n = 0; n < 2; ++n) {
    const int co = wid * 32 + n * 16 + g4 * 4;
#pragma unroll
    for (int m = 0; m < 4; ++m) {
      const int pl = m * 16 + l15;
      float* o = out + (size_t)(b * C_OUT + co) * 4096 + y0 * 64 + pl;
#pragma unroll
      for (int i = 0; i < 4; ++i)
        o[(size_t)i * 4096] = acc[n][m][i] + base_b[co + i];
    }
  }
}

extern "C" void kernel_launch(void* const* d_in, const int* in_sizes, int n_in,
                              void* d_out, int out_size, void* d_ws, size_t ws_size,
                              hipStream_t stream) {
  const float* x    = (const float*)d_in[0];
  const float* grid = (const float*)d_in[1];
  const float* sw   = (const float*)d_in[2];
  const float* bw   = (const float*)d_in[3];
  const float* bb   = (const float*)d_in[4];
  float* out = (float*)d_out;

  __bf16* wt3 = (__bf16*)d_ws;
  __bf16* xe  = (__bf16*)((char*)d_ws + XE_OFF);
  __bf16* se  = (__bf16*)((char*)d_ws + SE_OFF);

  prep_wt<<<NSTEPS, 256, 0, stream>>>(sw, bw, wt3);
  expand<<<(NEXP + 255) / 256, 256, 0, stream>>>(x, grid, xe, se);
  kan_gemm<<<512, 256, 0, stream>>>(xe, se, wt3, bb, out);
}

// Round 8
// 78.847 us; speedup vs baseline: 1.4988x; 1.1080x over previous
//
#include <hip/hip_runtime.h>

#define C_IN   64
#define HW_DIM 64
#define C_OUT  128
#define NG     8
#define KSPL   4608     // 576 * 8
#define BM     64       // pixels per block = one image row
#define NSPL_STEPS 72   // KSPL / 64
#define NSTEPS 81
#define NPAD   66
#define NEXP   (8 * C_IN * NPAD * NPAD)   // 2,230,272 padded elements

// d_ws layout (bytes)
#define WT_BYTES 1327104                  // 81*128*64*2
#define XE_OFF   WT_BYTES
#define XE_BYTES (NEXP * NG * 2)          // 35,684,352
#define SE_OFF   (XE_OFF + XE_BYTES)

typedef __attribute__((ext_vector_type(8))) __bf16 bf16x8;
typedef __attribute__((ext_vector_type(4))) float  f32x4;

// --------------------------------------------------------------------------
// Weight prep: pack spline_w ++ base_w into per-wave MFMA-fragment order for
// the 4-wave gemm: wt3[step][wc(4)][n(2)][ks(2)][lane(64)][8], value=W[co][k],
// co = wc*32 + n*16 + (lane&15), k = step*64 + ks*32 + (lane>>4)*8 + e.
// --------------------------------------------------------------------------
__global__ __launch_bounds__(256)
void prep_wt(const float* __restrict__ sw, const float* __restrict__ bw,
             __bf16* __restrict__ wt3)
{
  const int step = blockIdx.x;
  const int t    = threadIdx.x;
  const int wc   = t >> 6;
  const int lane = t & 63;
  const int l15  = lane & 15;
  const int g4   = lane >> 4;
#pragma unroll
  for (int n = 0; n < 2; ++n)
#pragma unroll
    for (int ks = 0; ks < 2; ++ks) {
      const int co = wc * 32 + n * 16 + l15;
      bf16x8 v;
#pragma unroll
      for (int e = 0; e < 8; ++e) {
        const int k = step * 64 + ks * 32 + g4 * 8 + e;
        float f;
        if (k < KSPL) f = sw[(size_t)k * C_OUT + co];
        else          f = bw[(size_t)(k - KSPL) * C_OUT + co];
        v[e] = (__bf16)f;
      }
      *(bf16x8*)(wt3 + (size_t)step * 8192 + wc * 2048 + (n * 2 + ks) * 512
                 + lane * 8) = v;
    }
}

// --------------------------------------------------------------------------
// Basis/silu expansion: XE[bc][yp][xp][8], SE[bc][yp][xp]; halo = p=0 values.
// --------------------------------------------------------------------------
__global__ __launch_bounds__(256)
void expand(const float* __restrict__ x, const float* __restrict__ grid,
            __bf16* __restrict__ xe, __bf16* __restrict__ se)
{
  const int idx = blockIdx.x * 256 + threadIdx.x;
  if (idx >= NEXP) return;
  const int xp = idx % NPAD;
  const int r  = idx / NPAD;
  const int yp = r % NPAD;
  const int bc = r / NPAD;

  float p = 0.f;
  if (xp >= 1 && xp <= HW_DIM && yp >= 1 && yp <= HW_DIM)
    p = x[(size_t)bc * (HW_DIM * HW_DIM) + (yp - 1) * HW_DIM + (xp - 1)];

  bf16x8 v;
#pragma unroll
  for (int g = 0; g < NG; ++g) {
    const float z = 1.75f * (p - grid[g]);
    v[g] = (__bf16)__expf(-z * z);
  }
  *(bf16x8*)(xe + (size_t)idx * NG) = v;
  const float e = __expf(-p);
  se[idx] = (__bf16)(p * __builtin_amdgcn_rcpf(1.f + e));
}

static __device__ __forceinline__ void gload16(const __bf16* g, __bf16* l) {
  __builtin_amdgcn_global_load_lds(
      (const __attribute__((address_space(1))) void*)g,
      (__attribute__((address_space(3))) void*)l, 16, 0, 0);
}

// counted-vmcnt barrier (T4): keep 6 newest VMEM ops in flight across it
#define WAITBAR6() do {                                      \
    asm volatile("s_waitcnt vmcnt(6)" ::: "memory");         \
    __builtin_amdgcn_s_barrier();                            \
    __builtin_amdgcn_sched_barrier(0);                       \
  } while (0)

// --------------------------------------------------------------------------
// GEMM: 512 blocks (1 image row) x 4 waves (64px x 32co each).
// Spline (72 steps): distance-2 pipeline. Per step/thread exactly 6 VMEM ops
// (2 global_load_lds for A into 3-deep LDS ring + 4 b128 B-frag loads into 3
// named register sets). Barrier = s_waitcnt vmcnt(6) + raw s_barrier: the
// current step's 6 prefetch loads stay in flight across the barrier (never
// drain to 0 in the main loop). Base (9 steps): LDS gathers + __syncthreads.
// --------------------------------------------------------------------------
__global__ __launch_bounds__(256, 2)
void kan_gemm(const __bf16* __restrict__ xe, const __bf16* __restrict__ se,
              const __bf16* __restrict__ wt3, const float* __restrict__ base_b,
              float* __restrict__ out)
{
  __shared__ __align__(16) __bf16 As[3][BM][64];   // 3 x 8 KB ring
  __shared__ int tbl[576];                         // c*4356 + kh*66 + kw

  const int t    = threadIdx.x;
  const int lane = t & 63;
  const int wid  = t >> 6;              // 0..3
  const int l15  = lane & 15;
  const int g4   = lane >> 4;

  // bijective XCD swizzle: 512 blocks = 8 XCDs x 64 -> one image per XCD
  const int bid = blockIdx.x;
  const int swz = (bid & 7) * 64 + (bid >> 3);
  const int b   = swz >> 6;             // image
  const int y0  = swz & 63;             // image row

  for (int f = t; f < 576; f += 256) {
    const int c  = f / 9;
    const int j  = f - 9 * c;
    const int kh = j / 3;
    const int kw = j - 3 * kh;
    tbl[f] = c * 4356 + kh * 66 + kw;
  }

  const int ROW = b * 278784 + y0 * 66;

  // A-staging: granule s = pass*256 + t holds (px = s>>3, gslot = s&7);
  // slot (px,gslot) must contain feature q = gslot ^ (px&7)  (G21 pre-swizzle)
  const int qsrc  = (lane & 7) ^ ((lane >> 3) & 7);
  const int pbase = (wid << 3) + (lane >> 3);

  f32x4 acc[2][4];
#pragma unroll
  for (int n = 0; n < 2; ++n)
#pragma unroll
    for (int m = 0; m < 4; ++m)
      acc[n][m] = f32x4{0.f, 0.f, 0.f, 0.f};

  auto stageA = [&](int buf, int step) {
    const int off = ROW + tbl[step * 8 + qsrc] + pbase;
    __bf16* dst = &As[buf][0][0] + t * 8;
    gload16(xe + (size_t)off * 8,        dst);
    gload16(xe + (size_t)(off + 32) * 8, dst + 2048);   // pass 1: px += 32
  };

  auto loadB = [&](bf16x8 (&wf)[2][2], int step) {
    const __bf16* wb = wt3 + (size_t)step * 8192 + wid * 2048 + lane * 8;
#pragma unroll
    for (int n = 0; n < 2; ++n)
#pragma unroll
      for (int ks = 0; ks < 2; ++ks)
        wf[n][ks] = *(const bf16x8*)(wb + (n * 2 + ks) * 512);
  };

  auto compute = [&](int buf, bf16x8 (&wf)[2][2]) {
    bf16x8 xf[4][2];
#pragma unroll
    for (int ks = 0; ks < 2; ++ks)
#pragma unroll
      for (int m = 0; m < 4; ++m) {
        const int pr = m * 16 + l15;
        xf[m][ks] = *(const bf16x8*)(&As[buf][pr][(((ks * 4 + g4) ^ (pr & 7)) * 8)]);
      }
#pragma unroll
    for (int ks = 0; ks < 2; ++ks)
#pragma unroll
      for (int n = 0; n < 2; ++n)
#pragma unroll
        for (int m = 0; m < 4; ++m)
          acc[n][m] = __builtin_amdgcn_mfma_f32_16x16x32_bf16(
              wf[n][ks], xf[m][ks], acc[n][m], 0, 0, 0);
  };

  __syncthreads();                      // tbl ready

  // ---- spline phase: distance-2 pipeline, counted-vmcnt barriers ----
  bf16x8 wA[2][2], wB[2][2], wC[2][2];
  stageA(0, 0); loadB(wA, 0);           // 6 VMEM ops
  stageA(1, 1); loadB(wB, 1);           // 6 VMEM ops
  WAITBAR6();                           // A(0)/B(0) landed; A(1)/B(1) in flight

  for (int s = 0; s < 69; s += 3) {
    stageA(2, s + 2); loadB(wC, s + 2);
    compute(0, wA);
    WAITBAR6();
    stageA(0, s + 3); loadB(wA, s + 3);
    compute(1, wB);
    WAITBAR6();
    stageA(1, s + 4); loadB(wB, s + 4);
    compute(2, wC);
    WAITBAR6();
  }
  // steps 69..71 (A69/buf0,A70/buf1 staged; stage 71 here)
  stageA(2, 71); loadB(wC, 71);
  compute(0, wA);                       // step 69
  WAITBAR6();                           // A(70) landed
  compute(1, wB);                       // step 70
  asm volatile("s_waitcnt vmcnt(0)" ::: "memory");
  __builtin_amdgcn_s_barrier();
  __builtin_amdgcn_sched_barrier(0);
  compute(2, wC);                       // step 71

  // ---- base phase: silu(p) patches via LDS (9 steps) ----
  const int ROWs = ROW + (t & 63);
  auto stageBase = [&](int buf, int bs) {
    const int px = t & 63;
#pragma unroll
    for (int h = 0; h < 2; ++h) {
      const int q = (t >> 6) + h * 4;   // granule 0..7 over 2 passes
      bf16x8 v;
#pragma unroll
      for (int jj = 0; jj < 8; ++jj) {
        const int f = (bs - NSPL_STEPS) * 64 + q * 8 + jj;
        v[jj] = se[(size_t)(ROWs + tbl[f])];
      }
      *(bf16x8*)(&As[buf][px][(q ^ (px & 7)) * 8]) = v;
    }
  };

  stageBase(0, NSPL_STEPS);             // writes buf0 (safe: others read buf1/2)
  __syncthreads();
  for (int bs = NSPL_STEPS; bs < NSTEPS; ++bs) {
    const int cb = (bs - NSPL_STEPS) & 1;
    if (bs + 1 < NSTEPS) stageBase(cb ^ 1, bs + 1);
    loadB(wA, bs);
    compute(cb, wA);
    __syncthreads();
  }

  // ---- epilogue: D[co][pix]; l15 -> consecutive x: coalesced ----
#pragma unroll
  for (int n = 0; n < 2; ++n) {
    const int co = wid * 32 + n * 16 + g4 * 4;
#pragma unroll
    for (int m = 0; m < 4; ++m) {
      const int pl = m * 16 + l15;
      float* o = out + (size_t)(b * C_OUT + co) * 4096 + y0 * 64 + pl;
#pragma unroll
      for (int i = 0; i < 4; ++i)
        o[(size_t)i * 4096] = acc[n][m][i] + base_b[co + i];
    }
  }
}

extern "C" void kernel_launch(void* const* d_in, const int* in_sizes, int n_in,
                              void* d_out, int out_size, void* d_ws, size_t ws_size,
                              hipStream_t stream) {
  const float* x    = (const float*)d_in[0];
  const float* grid = (const float*)d_in[1];
  const float* sw   = (const float*)d_in[2];
  const float* bw   = (const float*)d_in[3];
  const float* bb   = (const float*)d_in[4];
  float* out = (float*)d_out;

  __bf16* wt3 = (__bf16*)d_ws;
  __bf16* xe  = (__bf16*)((char*)d_ws + XE_OFF);
  __bf16* se  = (__bf16*)((char*)d_ws + SE_OFF);

  prep_wt<<<NSTEPS, 256, 0, stream>>>(sw, bw, wt3);
  expand<<<(NEXP + 255) / 256, 256, 0, stream>>>(x, grid, xe, se);
  kan_gemm<<<512, 256, 0, stream>>>(xe, se, wt3, bb, out);
}